// Round 4
// baseline (178.598 us; speedup 1.0000x reference)
//
#include <hip/hip_runtime.h>

#define BGRAPH  16
#define NPG     8192     // 2^13 nodes per graph
#define DIM     256
#define KKEEP   4096     // 2^12 kept per graph
#define TOTALN  (BGRAPH * NPG)     // 131072
#define TOTKEEP (BGRAPH * KKEEP)   // 65536
#define NEDGE   2097152

using u16 = unsigned short;
using u32 = unsigned int;
using u64 = unsigned long long;

// ---------------- kernel 1: score = tanh((x . w) / ||w||) -------------------
// one wave per row; f64 accumulation (boundary-rank robustness), f32 finish
// to reproduce the reference's f32 score quantization.
__global__ __launch_bounds__(256) void k_score(const float* __restrict__ x,
                                               const float* __restrict__ w,
                                               float* __restrict__ score) {
  int gid  = blockIdx.x * 256 + threadIdx.x;
  int row  = gid >> 6;
  int lane = gid & 63;
  const float4 x4 = *reinterpret_cast<const float4*>(x + (size_t)row * DIM + lane * 4);
  const float4 w4 = *reinterpret_cast<const float4*>(w + lane * 4);
  double dot = (double)x4.x * w4.x + (double)x4.y * w4.y
             + (double)x4.z * w4.z + (double)x4.w * w4.w;
  double w2  = (double)w4.x * w4.x + (double)w4.y * w4.y
             + (double)w4.z * w4.z + (double)w4.w * w4.w;
  #pragma unroll
  for (int off = 32; off > 0; off >>= 1) {
    dot += __shfl_xor(dot, off, 64);
    w2  += __shfl_xor(w2,  off, 64);
  }
  if (lane == 0) score[row] = tanhf((float)(dot / sqrt(w2)));
}

// ---------------- kernel 2: exact stable per-graph rank ---------------------
// 16 blocks/graph x 512 threads; key = (desc-sortable score bits << 13) | idx
// (unique) -> rank = #{j : key_j < key_i} reproduces jax.lax.top_k order
// (descending, ties -> lower index). Output: map16[node] = local rank if kept
// else 0xFFFF. (rank <= 4095 so no sentinel collision.)
__global__ __launch_bounds__(512) void k_rank(const float* __restrict__ score,
                                              u16* __restrict__ map16) {
  __shared__ u64 keys[NPG];                      // 64 KB
  const int g     = blockIdx.x >> 4;
  const int chunk = blockIdx.x & 15;
  const float* gs = score + (size_t)g * NPG;
  for (int i = threadIdx.x; i < NPG; i += 512) {
    u32 b  = __float_as_uint(gs[i]);
    u32 s  = b ^ ((b & 0x80000000u) ? 0xFFFFFFFFu : 0x80000000u);  // asc-sortable
    u32 kd = ~s;                                                    // desc-sortable
    keys[i] = ((u64)kd << 13) | (u32)i;
  }
  __syncthreads();
  const int r  = chunk * 512 + (int)threadIdx.x;
  const u64 Kr = keys[r];
  int cnt = 0;
  #pragma unroll 8
  for (int j = 0; j < NPG; j += 2) {             // same addr all lanes -> LDS broadcast
    u64 a = keys[j];
    u64 b = keys[j + 1];
    cnt += (a < Kr);
    cnt += (b < Kr);
  }
  map16[g * NPG + r] = (cnt < KKEEP) ? (u16)cnt : (u16)0xFFFFu;
}

// ---------------- kernel 3: inverted gather (f32 out) -----------------------
// one wave per INPUT node; kept nodes write their gated row to x_out[nid].
// Unique ranks guarantee every output row is written exactly once.
__global__ __launch_bounds__(256) void k_gather(const float* __restrict__ x,
                                                const float* __restrict__ score,
                                                const u16* __restrict__ map16,
                                                float* __restrict__ x_out) {
  int gid  = blockIdx.x * 256 + threadIdx.x;
  int node = gid >> 6;
  int lane = gid & 63;
  u16 rk = map16[node];
  if (rk == 0xFFFFu) return;
  int nid = ((node >> 13) << 12) | (int)rk;      // graph*K + rank
  float val = score[node];
  const float4 v = *reinterpret_cast<const float4*>(x + (size_t)node * DIM + lane * 4);
  float4 o;
  o.x = v.x * val; o.y = v.y * val; o.z = v.z * val; o.w = v.w * val;
  *reinterpret_cast<float4*>(x_out + (size_t)nid * DIM + lane * 4) = o;
}

// ---------------- kernel 4: edge filter + reindex (f32 out) -----------------
__global__ __launch_bounds__(256) void k_edges(const int* __restrict__ ei,
                                               const u16* __restrict__ map16,
                                               float* __restrict__ e_out) {
  int e = blockIdx.x * 256 + threadIdx.x;
  int a = ei[e];
  int b = ei[NEDGE + e];
  u16 ra = map16[a];
  u16 rb = map16[b];
  bool kept = (ra != 0xFFFFu) && (rb != 0xFFFFu);
  e_out[e]         = kept ? (float)(((a >> 13) << 12) | (int)ra) : -1.0f;
  e_out[NEDGE + e] = kept ? (float)(((b >> 13) << 12) | (int)rb) : -1.0f;
}

// ---------------- kernel 5: batch_out (runs last, clobbers map16 staging) ---
__global__ __launch_bounds__(256) void k_batch(float* __restrict__ b_out) {
  int i = blockIdx.x * 256 + threadIdx.x;
  b_out[i] = (float)(i >> 12);                   // nid / K = graph id
}

extern "C" void kernel_launch(void* const* d_in, const int* in_sizes, int n_in,
                              void* d_out, int out_size, void* d_ws, size_t ws_size,
                              hipStream_t stream) {
  const float* x  = nullptr;
  const int*   ei = nullptr;
  const float* w  = nullptr;
  for (int i = 0; i < n_in; ++i) {
    if      (in_sizes[i] == TOTALN * DIM) x  = (const float*)d_in[i];
    else if (in_sizes[i] == 2 * NEDGE)    ei = (const int*)d_in[i];
    else if (in_sizes[i] == DIM)          w  = (const float*)d_in[i];
  }

  // d_out: FLOAT32, layout [x_out 16777216 | e_out 4194304 | b_out 65536]
  float* out   = (float*)d_out;
  float* x_out = out;
  float* e_out = out + (size_t)TOTKEEP * DIM;    // f32 idx 16777216
  float* b_out = e_out + 2 * (size_t)NEDGE;      // f32 idx 20971520

  // zero-workspace staging inside d_out (each consumed before clobbered;
  // kernels serialize on the stream):
  float* score = e_out;                          // 512 KB at e_out head
  u16*   map16 = (u16*)b_out;                    // 256 KB = exactly b_out region

  hipLaunchKernelGGL(k_score,  dim3(TOTALN / 4),   dim3(256), 0, stream, x, w, score);
  hipLaunchKernelGGL(k_rank,   dim3(BGRAPH * 16),  dim3(512), 0, stream, score, map16);
  hipLaunchKernelGGL(k_gather, dim3(TOTALN / 4),   dim3(256), 0, stream, x, score, map16, x_out);
  hipLaunchKernelGGL(k_edges,  dim3(NEDGE / 256),  dim3(256), 0, stream, ei, map16, e_out);
  hipLaunchKernelGGL(k_batch,  dim3(TOTKEEP / 256),dim3(256), 0, stream, b_out);
}